// Round 1
// baseline (20763.925 us; speedup 1.0000x reference)
//
#include <hip/hip_runtime.h>

#define S   8192
#define HHH 512
#define EE  512
#define G4  2048
#define KT  5
#define NWG 16
#define NEGV (-10000.0f)

// ---------- helpers ----------
__device__ __forceinline__ float bf2f(unsigned short u) {
  union { unsigned int i; float f; } v; v.i = ((unsigned int)u) << 16; return v.f;
}
__device__ __forceinline__ unsigned short f2bf(float f) {
  union { float f; unsigned int i; } v; v.f = f;
  unsigned int u = v.i;
  unsigned int r = (u + 0x7FFFu + ((u >> 16) & 1u)) >> 16;   // RNE
  return (unsigned short)r;
}
__device__ __forceinline__ float sigmoidf_(float x) { return 1.0f / (1.0f + expf(-x)); }

// ---------- 1. input projections: xp = embed[sent] @ W_ih^T + b (bf16 out) ----------
__global__ __launch_bounds__(256) void ih_gemm(
    const float* __restrict__ embed, const int* __restrict__ sent,
    const float* __restrict__ Wf, const float* __restrict__ bf,
    const float* __restrict__ Wb, const float* __restrict__ bb,
    unsigned short* __restrict__ xpf, unsigned short* __restrict__ xpb)
{
  const int rev = blockIdx.z;
  const float* Wi = rev ? Wb : Wf;
  const float* bi = rev ? bb : bf;
  unsigned short* xp = rev ? xpb : xpf;

  __shared__ float At[16][68];
  __shared__ float Bt[16][68];
  __shared__ int sidx[64];

  const int tid = threadIdx.x;
  const int bm = blockIdx.x * 64;
  const int bn = blockIdx.y * 64;
  if (tid < 64) {
    int m = bm + tid;
    sidx[tid] = sent[rev ? (S - 1 - m) : m];
  }
  __syncthreads();

  const int tx = tid & 15, ty = tid >> 4;
  float acc[4][4];
#pragma unroll
  for (int i = 0; i < 4; i++)
#pragma unroll
    for (int j = 0; j < 4; j++) acc[i][j] = 0.f;

  const int lr = tid >> 2;
  const int lk = (tid & 3) * 4;

  for (int k0 = 0; k0 < EE; k0 += 16) {
    float4 a4 = *(const float4*)(embed + (size_t)sidx[lr] * EE + k0 + lk);
    float4 b4 = *(const float4*)(Wi + (size_t)(bn + lr) * EE + k0 + lk);
    At[lk + 0][lr] = a4.x; At[lk + 1][lr] = a4.y; At[lk + 2][lr] = a4.z; At[lk + 3][lr] = a4.w;
    Bt[lk + 0][lr] = b4.x; Bt[lk + 1][lr] = b4.y; Bt[lk + 2][lr] = b4.z; Bt[lk + 3][lr] = b4.w;
    __syncthreads();
#pragma unroll
    for (int kk = 0; kk < 16; kk++) {
      float4 av = *(const float4*)&At[kk][ty * 4];
      float4 bv = *(const float4*)&Bt[kk][tx * 4];
      float aa[4] = {av.x, av.y, av.z, av.w};
      float bbv[4] = {bv.x, bv.y, bv.z, bv.w};
#pragma unroll
      for (int i = 0; i < 4; i++)
#pragma unroll
        for (int j = 0; j < 4; j++) acc[i][j] += aa[i] * bbv[j];
    }
    __syncthreads();
  }
#pragma unroll
  for (int i = 0; i < 4; i++) {
    int m = bm + ty * 4 + i;
    ushort4 pack;
    unsigned short* ps = (unsigned short*)&pack;
#pragma unroll
    for (int j = 0; j < 4; j++) {
      int n = bn + tx * 4 + j;
      ps[j] = f2bf(acc[i][j] + bi[n]);
    }
    *(ushort4*)(xp + (size_t)m * G4 + bn + tx * 4) = pack;
  }
}

// ---------- 2. the sequential scan: 16 WGs per direction, W_hh in VGPRs ----------
__global__ __launch_bounds__(512, 2) void lstm_scan(
    const float* __restrict__ Whh_f, const float* __restrict__ Whh_b,
    const unsigned short* __restrict__ xp_f, const unsigned short* __restrict__ xp_b,
    const float* __restrict__ h0, const float* __restrict__ c0,
    float* __restrict__ Hf, float* __restrict__ Hb,
    int* __restrict__ cnt_f, int* __restrict__ cnt_b)
{
  const int wg = blockIdx.x;
  const int dir = wg >> 4;
  const int slice = wg & 15;
  const float* W = dir ? Whh_b : Whh_f;
  const unsigned short* xp = dir ? xp_b : xp_f;
  float* H = dir ? Hb : Hf;
  int* cnt = dir ? cnt_b : cnt_f;
  const int U0 = slice * 32;

  const int tid = threadIdx.x;
  const int row = tid >> 2;        // 0..127 local gate-row
  const int q = tid & 3;           // k-quarter
  const int g = row >> 5;          // gate 0..3 (i,f,g,o)
  const int ul = row & 31;         // local unit
  const int grow = g * HHH + U0 + ul;

  // W slice resident in 128 VGPRs
  float4 w4[32];
  {
    const float4* wsrc = (const float4*)(W + (size_t)grow * HHH + q * 128);
#pragma unroll
    for (int k = 0; k < 32; k++) w4[k] = wsrc[k];
  }

  __shared__ float h_lds[4 * 132];     // 4 chunks of 128, pad 4 (bank-clean b128)
  __shared__ float gates_lds[128];

  float c_reg = (tid < 32) ? c0[dir * HHH + U0 + tid] : 0.f;

  for (int t = 0; t < S; ++t) {
    // prefetch this step's xp early (no dependency on h)
    unsigned short rxi = 0, rxf = 0, rxg = 0, rxo = 0;
    if (tid < 32) {
      const unsigned short* xr = xp + (size_t)t * G4 + U0 + tid;
      rxi = xr[0]; rxf = xr[512]; rxg = xr[1024]; rxo = xr[1536];
    }
    if (t > 0) {
      if (tid == 0) {
        while (__hip_atomic_load(&cnt[t - 1], __ATOMIC_ACQUIRE, __HIP_MEMORY_SCOPE_AGENT) < NWG)
          __builtin_amdgcn_s_sleep(1);
      }
      __syncthreads();
      float hv = __hip_atomic_load(&H[(size_t)(t - 1) * HHH + tid], __ATOMIC_RELAXED,
                                   __HIP_MEMORY_SCOPE_AGENT);
      h_lds[(tid >> 7) * 132 + (tid & 127)] = hv;
    } else {
      h_lds[(tid >> 7) * 132 + (tid & 127)] = h0[dir * HHH + tid];
    }
    __syncthreads();

    // matvec: each thread 128 MACs from registers
    float acc = 0.f;
    const float4* hp = (const float4*)&h_lds[q * 132];
#pragma unroll
    for (int k = 0; k < 32; k++) {
      float4 h4 = hp[k];
      acc += w4[k].x * h4.x;
      acc += w4[k].y * h4.y;
      acc += w4[k].z * h4.z;
      acc += w4[k].w * h4.w;
    }
    acc += __shfl_xor(acc, 1);
    acc += __shfl_xor(acc, 2);
    if (q == 0) gates_lds[row] = acc;
    __syncthreads();

    if (tid < 32) {
      float pi = gates_lds[tid] + bf2f(rxi);
      float pf = gates_lds[32 + tid] + bf2f(rxf);
      float pg = gates_lds[64 + tid] + bf2f(rxg);
      float po = gates_lds[96 + tid] + bf2f(rxo);
      float i_ = sigmoidf_(pi);
      float f_ = sigmoidf_(pf);
      float g_ = tanhf(pg);
      float o_ = sigmoidf_(po);
      c_reg = f_ * c_reg + i_ * g_;
      float h = o_ * tanhf(c_reg);
      __hip_atomic_store(&H[(size_t)t * HHH + U0 + tid], h, __ATOMIC_RELAXED,
                         __HIP_MEMORY_SCOPE_AGENT);
    }
    __syncthreads();
    if (tid == 0)
      __hip_atomic_fetch_add(&cnt[t], 1, __ATOMIC_RELEASE, __HIP_MEMORY_SCOPE_AGENT);
  }
}

// ---------- 3. feats[t] = [Hf[t] | Hb[S-1-t]] @ W_out^T + b_out ----------
__global__ __launch_bounds__(256) void feats_kernel(
    const float* __restrict__ Hf, const float* __restrict__ Hb,
    const float* __restrict__ Wo, const float* __restrict__ bo,
    float* __restrict__ feats)
{
  const int t = blockIdx.x * 4 + (threadIdx.x >> 6);
  const int lane = threadIdx.x & 63;
  float p0 = 0, p1 = 0, p2 = 0, p3 = 0, p4 = 0;
#pragma unroll
  for (int i = 0; i < 16; i++) {
    int j = lane + i * 64;
    float hv = (i < 8) ? Hf[(size_t)t * HHH + j]
                       : Hb[(size_t)(S - 1 - t) * HHH + (j - HHH)];
    p0 += Wo[0 * 1024 + j] * hv;
    p1 += Wo[1 * 1024 + j] * hv;
    p2 += Wo[2 * 1024 + j] * hv;
    p3 += Wo[3 * 1024 + j] * hv;
    p4 += Wo[4 * 1024 + j] * hv;
  }
#pragma unroll
  for (int off = 32; off; off >>= 1) {
    p0 += __shfl_xor(p0, off);
    p1 += __shfl_xor(p1, off);
    p2 += __shfl_xor(p2, off);
    p3 += __shfl_xor(p3, off);
    p4 += __shfl_xor(p4, off);
  }
  if (lane == 0) {
    float* f = feats + (size_t)t * KT;
    f[0] = p0 + bo[0]; f[1] = p1 + bo[1]; f[2] = p2 + bo[2];
    f[3] = p3 + bo[3]; f[4] = p4 + bo[4];
  }
}

// ---------- 4. Viterbi DP (5 lanes) + parallel backtrack via map composition ----------
__device__ __forceinline__ unsigned comp_map(unsigned f, unsigned gmap) {
  unsigned h = 0;
#pragma unroll
  for (int j = 0; j < 5; j++) {
    unsigned gj = (gmap >> (4 * j)) & 15u;
    unsigned fg = (f >> (4 * gj)) & 15u;
    h |= fg << (4 * j);
  }
  return h;
}

__global__ __launch_bounds__(256) void viterbi_kernel(
    const float* __restrict__ feats, const float* __restrict__ T,
    float* __restrict__ out)
{
  __shared__ unsigned char bp_lds[S * 5];
  __shared__ unsigned maps[256];
  __shared__ int best_s;

  const int tid = threadIdx.x;

  if (tid < 5) {
    const int n = tid;
    float Tr0 = T[n * 5 + 0], Tr1 = T[n * 5 + 1], Tr2 = T[n * 5 + 2],
          Tr3 = T[n * 5 + 3], Tr4 = T[n * 5 + 4];
    float T4 = T[4 * 5 + n];
    float fv = (n == 3) ? 0.f : NEGV;
    float cur[8], nxt[8];
#pragma unroll
    for (int i = 0; i < 8; i++) cur[i] = feats[i * 5 + n];
    for (int t0 = 0; t0 < S; t0 += 8) {
#pragma unroll
      for (int i = 0; i < 8; i++) {
        int tn = t0 + 8 + i;
        nxt[i] = (tn < S) ? feats[tn * 5 + n] : 0.f;
      }
#pragma unroll
      for (int i = 0; i < 8; i++) {
        int t = t0 + i;
        float s0 = __shfl(fv, 0) + Tr0;
        float s1 = __shfl(fv, 1) + Tr1;
        float s2 = __shfl(fv, 2) + Tr2;
        float s3 = __shfl(fv, 3) + Tr3;
        float s4 = __shfl(fv, 4) + Tr4;
        float best = s0; int b = 0;
        if (s1 > best) { best = s1; b = 1; }
        if (s2 > best) { best = s2; b = 2; }
        if (s3 > best) { best = s3; b = 3; }
        if (s4 > best) { best = s4; b = 4; }
        fv = best + cur[i];
        bp_lds[t * 5 + n] = (unsigned char)b;
      }
#pragma unroll
      for (int i = 0; i < 8; i++) cur[i] = nxt[i];
    }
    float term = fv + T4;
    float t0v = __shfl(term, 0), t1v = __shfl(term, 1), t2v = __shfl(term, 2),
          t3v = __shfl(term, 3), t4v = __shfl(term, 4);
    float bbest = t0v; int bt = 0;
    if (t1v > bbest) { bbest = t1v; bt = 1; }
    if (t2v > bbest) { bbest = t2v; bt = 2; }
    if (t3v > bbest) { bbest = t3v; bt = 3; }
    if (t4v > bbest) { bbest = t4v; bt = 4; }
    if (n == 0) { out[0] = bbest; best_s = bt; }
  }
  __syncthreads();

  // suffix composition of backpointer maps; a[0] := identity
  unsigned Q = 0x43210u;
  const int d = tid;
  for (int i = 31; i >= 0; i--) {
    int t = d * 32 + i;
    unsigned m;
    if (t == 0) m = 0x43210u;
    else {
      const unsigned char* bp = &bp_lds[t * 5];
      m = (unsigned)bp[0] | ((unsigned)bp[1] << 4) | ((unsigned)bp[2] << 8) |
          ((unsigned)bp[3] << 12) | ((unsigned)bp[4] << 16);
    }
    Q = comp_map(m, Q);
  }
  maps[d] = Q;
  __syncthreads();
#pragma unroll
  for (int off = 1; off < 256; off <<= 1) {
    unsigned mine = maps[d];
    unsigned oth = (d + off < 256) ? maps[d + off] : 0x43210u;
    __syncthreads();
    maps[d] = comp_map(mine, oth);
    __syncthreads();
  }
  unsigned Ex = (d < 255) ? maps[d + 1] : 0x43210u;
  int tag = (Ex >> (4 * best_s)) & 15;
  out[1 + d * 32 + 31] = (float)tag;
  for (int i = 30; i >= 0; i--) {
    int t = d * 32 + i;
    tag = bp_lds[(t + 1) * 5 + tag];
    out[1 + t] = (float)tag;
  }
}

// ---------- launch ----------
extern "C" void kernel_launch(void* const* d_in, const int* in_sizes, int n_in,
                              void* d_out, int out_size, void* d_ws, size_t ws_size,
                              hipStream_t stream)
{
  const int*   sentence = (const int*)d_in[0];
  const float* embed    = (const float*)d_in[1];
  const float* W_ih_f   = (const float*)d_in[2];
  const float* W_hh_f   = (const float*)d_in[3];
  const float* b_f      = (const float*)d_in[4];
  const float* W_ih_b   = (const float*)d_in[5];
  const float* W_hh_b   = (const float*)d_in[6];
  const float* b_b      = (const float*)d_in[7];
  const float* W_out    = (const float*)d_in[8];
  const float* b_out    = (const float*)d_in[9];
  const float* trans    = (const float*)d_in[10];
  const float* h0       = (const float*)d_in[11];
  const float* c0       = (const float*)d_in[12];
  float* out = (float*)d_out;

  char* ws = (char*)d_ws;
  size_t off = 0;
  unsigned short* xp_f = (unsigned short*)(ws + off); off += (size_t)S * G4 * 2;
  unsigned short* xp_b = (unsigned short*)(ws + off); off += (size_t)S * G4 * 2;
  float* Hf    = (float*)(ws + off); off += (size_t)S * HHH * 4;
  float* Hb    = (float*)(ws + off); off += (size_t)S * HHH * 4;
  float* feats = (float*)(ws + off); off += (size_t)S * KT * 4;
  int* cnt_f   = (int*)(ws + off); off += (size_t)S * 4;
  int* cnt_b   = (int*)(ws + off); off += (size_t)S * 4;
  if (ws_size < off) return;  // insufficient workspace; bail (bench will flag)

  // counters MUST be zero before the scan kernel each call
  hipMemsetAsync(cnt_f, 0, (size_t)S * 4 * 2, stream);

  dim3 gg(S / 64, G4 / 64, 2);
  ih_gemm<<<gg, 256, 0, stream>>>(embed, sentence, W_ih_f, b_f, W_ih_b, b_b, xp_f, xp_b);
  lstm_scan<<<32, 512, 0, stream>>>(W_hh_f, W_hh_b, xp_f, xp_b, h0, c0, Hf, Hb, cnt_f, cnt_b);
  feats_kernel<<<S / 4, 256, 0, stream>>>(Hf, Hb, W_out, b_out, feats);
  viterbi_kernel<<<1, 256, 0, stream>>>(feats, trans, out);
}

// Round 2
// 16346.320 us; speedup vs baseline: 1.2703x; 1.2703x over previous
//
#include <hip/hip_runtime.h>

#define S   8192
#define HHH 512
#define EE  512
#define G4  2048
#define KT  5
#define NWG 16
#define NEGV (-10000.0f)
#define SENT 0xFFFFFFFFu   // NaN bit pattern used as "not yet written"

// ---------- helpers ----------
__device__ __forceinline__ float bf2f(unsigned short u) {
  union { unsigned int i; float f; } v; v.i = ((unsigned int)u) << 16; return v.f;
}
__device__ __forceinline__ unsigned short f2bf(float f) {
  union { float f; unsigned int i; } v; v.f = f;
  unsigned int u = v.i;
  unsigned int r = (u + 0x7FFFu + ((u >> 16) & 1u)) >> 16;   // RNE
  return (unsigned short)r;
}
__device__ __forceinline__ float sigmoidf_(float x) { return 1.0f / (1.0f + expf(-x)); }

// ---------- 1. input projections: xp = embed[sent] @ W_ih^T + b (bf16 out) ----------
__global__ __launch_bounds__(256) void ih_gemm(
    const float* __restrict__ embed, const int* __restrict__ sent,
    const float* __restrict__ Wf, const float* __restrict__ bf,
    const float* __restrict__ Wb, const float* __restrict__ bb,
    unsigned short* __restrict__ xpf, unsigned short* __restrict__ xpb)
{
  const int rev = blockIdx.z;
  const float* Wi = rev ? Wb : Wf;
  const float* bi = rev ? bb : bf;
  unsigned short* xp = rev ? xpb : xpf;

  __shared__ float At[16][68];
  __shared__ float Bt[16][68];
  __shared__ int sidx[64];

  const int tid = threadIdx.x;
  const int bm = blockIdx.x * 64;
  const int bn = blockIdx.y * 64;
  if (tid < 64) {
    int m = bm + tid;
    sidx[tid] = sent[rev ? (S - 1 - m) : m];
  }
  __syncthreads();

  const int tx = tid & 15, ty = tid >> 4;
  float acc[4][4];
#pragma unroll
  for (int i = 0; i < 4; i++)
#pragma unroll
    for (int j = 0; j < 4; j++) acc[i][j] = 0.f;

  const int lr = tid >> 2;
  const int lk = (tid & 3) * 4;

  for (int k0 = 0; k0 < EE; k0 += 16) {
    float4 a4 = *(const float4*)(embed + (size_t)sidx[lr] * EE + k0 + lk);
    float4 b4 = *(const float4*)(Wi + (size_t)(bn + lr) * EE + k0 + lk);
    At[lk + 0][lr] = a4.x; At[lk + 1][lr] = a4.y; At[lk + 2][lr] = a4.z; At[lk + 3][lr] = a4.w;
    Bt[lk + 0][lr] = b4.x; Bt[lk + 1][lr] = b4.y; Bt[lk + 2][lr] = b4.z; Bt[lk + 3][lr] = b4.w;
    __syncthreads();
#pragma unroll
    for (int kk = 0; kk < 16; kk++) {
      float4 av = *(const float4*)&At[kk][ty * 4];
      float4 bv = *(const float4*)&Bt[kk][tx * 4];
      float aa[4] = {av.x, av.y, av.z, av.w};
      float bbv[4] = {bv.x, bv.y, bv.z, bv.w};
#pragma unroll
      for (int i = 0; i < 4; i++)
#pragma unroll
        for (int j = 0; j < 4; j++) acc[i][j] += aa[i] * bbv[j];
    }
    __syncthreads();
  }
#pragma unroll
  for (int i = 0; i < 4; i++) {
    int m = bm + ty * 4 + i;
    ushort4 pack;
    unsigned short* ps = (unsigned short*)&pack;
#pragma unroll
    for (int j = 0; j < 4; j++) {
      int n = bn + tx * 4 + j;
      ps[j] = f2bf(acc[i][j] + bi[n]);
    }
    *(ushort4*)(xp + (size_t)m * G4 + bn + tx * 4) = pack;
  }
}

// ---------- 2. sequential scan: data-as-flag handshake (NaN sentinel) ----------
// H buffers are pre-set to 0xFFFFFFFF (NaN). Producers store finite h values
// (relaxed, agent scope). Consumers spin-load their own element until it is
// not the sentinel — one MALL round trip total, no counters, no RMW, no fence.
__global__ __launch_bounds__(512, 2) void lstm_scan(
    const float* __restrict__ Whh_f, const float* __restrict__ Whh_b,
    const unsigned short* __restrict__ xp_f, const unsigned short* __restrict__ xp_b,
    const float* __restrict__ h0, const float* __restrict__ c0,
    unsigned* __restrict__ Hf, unsigned* __restrict__ Hb)
{
  const int wg = blockIdx.x;
  const int dir = wg >> 4;
  const int slice = wg & 15;
  const float* W = dir ? Whh_b : Whh_f;
  const unsigned short* xp = dir ? xp_b : xp_f;
  unsigned* H = dir ? Hb : Hf;
  const int U0 = slice * 32;

  const int tid = threadIdx.x;
  const int row = tid >> 2;        // 0..127 local gate-row
  const int q = tid & 3;           // k-quarter
  const int g = row >> 5;          // gate 0..3 (i,f,g,o)
  const int ul = row & 31;         // local unit
  const int grow = g * HHH + U0 + ul;

  // W slice resident in registers
  float4 w4[32];
  {
    const float4* wsrc = (const float4*)(W + (size_t)grow * HHH + q * 128);
#pragma unroll
    for (int k = 0; k < 32; k++) w4[k] = wsrc[k];
  }

  __shared__ float h_lds[4 * 132];     // 4 chunks of 128, pad 4
  __shared__ float gates_lds[128];

  float c_reg = (tid < 32) ? c0[dir * HHH + U0 + tid] : 0.f;

  for (int t = 0; t < S; ++t) {
    // prefetch this step's xp early (no dependency on h)
    unsigned short rxi = 0, rxf = 0, rxg = 0, rxo = 0;
    if (tid < 32) {
      const unsigned short* xr = xp + (size_t)t * G4 + U0 + tid;
      rxi = xr[0]; rxf = xr[512]; rxg = xr[1024]; rxo = xr[1536];
    }
    if (t > 0) {
      // every lane polls its own element of h[t-1]; the poll IS the load
      unsigned v;
      const unsigned* src = &H[(size_t)(t - 1) * HHH + tid];
      do {
        v = __hip_atomic_load(src, __ATOMIC_RELAXED, __HIP_MEMORY_SCOPE_AGENT);
      } while (v == SENT);
      union { unsigned u; float f; } cv; cv.u = v;
      h_lds[(tid >> 7) * 132 + (tid & 127)] = cv.f;
    } else {
      h_lds[(tid >> 7) * 132 + (tid & 127)] = h0[dir * HHH + tid];
    }
    __syncthreads();

    // matvec: each thread 128 MACs from registers
    float acc = 0.f;
    const float4* hp = (const float4*)&h_lds[q * 132];
#pragma unroll
    for (int k = 0; k < 32; k++) {
      float4 h4 = hp[k];
      acc += w4[k].x * h4.x;
      acc += w4[k].y * h4.y;
      acc += w4[k].z * h4.z;
      acc += w4[k].w * h4.w;
    }
    acc += __shfl_xor(acc, 1);
    acc += __shfl_xor(acc, 2);
    if (q == 0) gates_lds[row] = acc;
    __syncthreads();

    if (tid < 32) {
      float pi = gates_lds[tid] + bf2f(rxi);
      float pf = gates_lds[32 + tid] + bf2f(rxf);
      float pg = gates_lds[64 + tid] + bf2f(rxg);
      float po = gates_lds[96 + tid] + bf2f(rxo);
      float i_ = sigmoidf_(pi);
      float f_ = sigmoidf_(pf);
      float g_ = tanhf(pg);
      float o_ = sigmoidf_(po);
      c_reg = f_ * c_reg + i_ * g_;
      float h = o_ * tanhf(c_reg);
      union { float f; unsigned u; } cv; cv.f = h;
      __hip_atomic_store(&H[(size_t)t * HHH + U0 + tid], cv.u, __ATOMIC_RELAXED,
                         __HIP_MEMORY_SCOPE_AGENT);
    }
    // no trailing barrier needed: next iteration's poll/syncthreads orders us
    __syncthreads();
  }
}

// ---------- 3. feats[t] = [Hf[t] | Hb[S-1-t]] @ W_out^T + b_out ----------
__global__ __launch_bounds__(256) void feats_kernel(
    const float* __restrict__ Hf, const float* __restrict__ Hb,
    const float* __restrict__ Wo, const float* __restrict__ bo,
    float* __restrict__ feats)
{
  const int t = blockIdx.x * 4 + (threadIdx.x >> 6);
  const int lane = threadIdx.x & 63;
  float p0 = 0, p1 = 0, p2 = 0, p3 = 0, p4 = 0;
#pragma unroll
  for (int i = 0; i < 16; i++) {
    int j = lane + i * 64;
    float hv = (i < 8) ? Hf[(size_t)t * HHH + j]
                       : Hb[(size_t)(S - 1 - t) * HHH + (j - HHH)];
    p0 += Wo[0 * 1024 + j] * hv;
    p1 += Wo[1 * 1024 + j] * hv;
    p2 += Wo[2 * 1024 + j] * hv;
    p3 += Wo[3 * 1024 + j] * hv;
    p4 += Wo[4 * 1024 + j] * hv;
  }
#pragma unroll
  for (int off = 32; off; off >>= 1) {
    p0 += __shfl_xor(p0, off);
    p1 += __shfl_xor(p1, off);
    p2 += __shfl_xor(p2, off);
    p3 += __shfl_xor(p3, off);
    p4 += __shfl_xor(p4, off);
  }
  if (lane == 0) {
    float* f = feats + (size_t)t * KT;
    f[0] = p0 + bo[0]; f[1] = p1 + bo[1]; f[2] = p2 + bo[2];
    f[3] = p3 + bo[3]; f[4] = p4 + bo[4];
  }
}

// ---------- 4. Viterbi DP (5 lanes) + parallel backtrack via map composition ----------
__device__ __forceinline__ unsigned comp_map(unsigned f, unsigned gmap) {
  unsigned h = 0;
#pragma unroll
  for (int j = 0; j < 5; j++) {
    unsigned gj = (gmap >> (4 * j)) & 15u;
    unsigned fg = (f >> (4 * gj)) & 15u;
    h |= fg << (4 * j);
  }
  return h;
}

__global__ __launch_bounds__(256) void viterbi_kernel(
    const float* __restrict__ feats, const float* __restrict__ T,
    float* __restrict__ out)
{
  __shared__ unsigned char bp_lds[S * 5];
  __shared__ unsigned maps[256];
  __shared__ int best_s;

  const int tid = threadIdx.x;

  if (tid < 5) {
    const int n = tid;
    float Tr0 = T[n * 5 + 0], Tr1 = T[n * 5 + 1], Tr2 = T[n * 5 + 2],
          Tr3 = T[n * 5 + 3], Tr4 = T[n * 5 + 4];
    float T4 = T[4 * 5 + n];
    float fv = (n == 3) ? 0.f : NEGV;
    float cur[8], nxt[8];
#pragma unroll
    for (int i = 0; i < 8; i++) cur[i] = feats[i * 5 + n];
    for (int t0 = 0; t0 < S; t0 += 8) {
#pragma unroll
      for (int i = 0; i < 8; i++) {
        int tn = t0 + 8 + i;
        nxt[i] = (tn < S) ? feats[tn * 5 + n] : 0.f;
      }
#pragma unroll
      for (int i = 0; i < 8; i++) {
        int t = t0 + i;
        float s0 = __shfl(fv, 0) + Tr0;
        float s1 = __shfl(fv, 1) + Tr1;
        float s2 = __shfl(fv, 2) + Tr2;
        float s3 = __shfl(fv, 3) + Tr3;
        float s4 = __shfl(fv, 4) + Tr4;
        float best = s0; int b = 0;
        if (s1 > best) { best = s1; b = 1; }
        if (s2 > best) { best = s2; b = 2; }
        if (s3 > best) { best = s3; b = 3; }
        if (s4 > best) { best = s4; b = 4; }
        fv = best + cur[i];
        bp_lds[t * 5 + n] = (unsigned char)b;
      }
#pragma unroll
      for (int i = 0; i < 8; i++) cur[i] = nxt[i];
    }
    float term = fv + T4;
    float t0v = __shfl(term, 0), t1v = __shfl(term, 1), t2v = __shfl(term, 2),
          t3v = __shfl(term, 3), t4v = __shfl(term, 4);
    float bbest = t0v; int bt = 0;
    if (t1v > bbest) { bbest = t1v; bt = 1; }
    if (t2v > bbest) { bbest = t2v; bt = 2; }
    if (t3v > bbest) { bbest = t3v; bt = 3; }
    if (t4v > bbest) { bbest = t4v; bt = 4; }
    if (n == 0) { out[0] = bbest; best_s = bt; }
  }
  __syncthreads();

  // suffix composition of backpointer maps; a[0] := identity
  unsigned Q = 0x43210u;
  const int d = tid;
  for (int i = 31; i >= 0; i--) {
    int t = d * 32 + i;
    unsigned m;
    if (t == 0) m = 0x43210u;
    else {
      const unsigned char* bp = &bp_lds[t * 5];
      m = (unsigned)bp[0] | ((unsigned)bp[1] << 4) | ((unsigned)bp[2] << 8) |
          ((unsigned)bp[3] << 12) | ((unsigned)bp[4] << 16);
    }
    Q = comp_map(m, Q);
  }
  maps[d] = Q;
  __syncthreads();
#pragma unroll
  for (int off = 1; off < 256; off <<= 1) {
    unsigned mine = maps[d];
    unsigned oth = (d + off < 256) ? maps[d + off] : 0x43210u;
    __syncthreads();
    maps[d] = comp_map(mine, oth);
    __syncthreads();
  }
  unsigned Ex = (d < 255) ? maps[d + 1] : 0x43210u;
  int tag = (Ex >> (4 * best_s)) & 15;
  out[1 + d * 32 + 31] = (float)tag;
  for (int i = 30; i >= 0; i--) {
    int t = d * 32 + i;
    tag = bp_lds[(t + 1) * 5 + tag];
    out[1 + t] = (float)tag;
  }
}

// ---------- launch ----------
extern "C" void kernel_launch(void* const* d_in, const int* in_sizes, int n_in,
                              void* d_out, int out_size, void* d_ws, size_t ws_size,
                              hipStream_t stream)
{
  const int*   sentence = (const int*)d_in[0];
  const float* embed    = (const float*)d_in[1];
  const float* W_ih_f   = (const float*)d_in[2];
  const float* W_hh_f   = (const float*)d_in[3];
  const float* b_f      = (const float*)d_in[4];
  const float* W_ih_b   = (const float*)d_in[5];
  const float* W_hh_b   = (const float*)d_in[6];
  const float* b_b      = (const float*)d_in[7];
  const float* W_out    = (const float*)d_in[8];
  const float* b_out    = (const float*)d_in[9];
  const float* trans    = (const float*)d_in[10];
  const float* h0       = (const float*)d_in[11];
  const float* c0       = (const float*)d_in[12];
  float* out = (float*)d_out;

  char* ws = (char*)d_ws;
  size_t off = 0;
  unsigned short* xp_f = (unsigned short*)(ws + off); off += (size_t)S * G4 * 2;
  unsigned short* xp_b = (unsigned short*)(ws + off); off += (size_t)S * G4 * 2;
  unsigned* Hf = (unsigned*)(ws + off); off += (size_t)S * HHH * 4;
  unsigned* Hb = (unsigned*)(ws + off); off += (size_t)S * HHH * 4;
  float* feats = (float*)(ws + off); off += (size_t)S * KT * 4;
  if (ws_size < off) return;

  // H must start as the NaN sentinel every call (graph replays don't re-poison)
  hipMemsetAsync(Hf, 0xFF, (size_t)S * HHH * 4 * 2, stream);

  dim3 gg(S / 64, G4 / 64, 2);
  ih_gemm<<<gg, 256, 0, stream>>>(embed, sentence, W_ih_f, b_f, W_ih_b, b_b, xp_f, xp_b);
  lstm_scan<<<32, 512, 0, stream>>>(W_hh_f, W_hh_b, xp_f, xp_b, h0, c0, Hf, Hb);
  feats_kernel<<<S / 4, 256, 0, stream>>>((const float*)Hf, (const float*)Hb, W_out, b_out, feats);
  viterbi_kernel<<<1, 256, 0, stream>>>(feats, trans, out);
}